// Round 1
// baseline (1721.247 us; speedup 1.0000x reference)
//
#include <hip/hip_runtime.h>
#include <hip/hip_bf16.h>

#define NN 4096
#define HD 128
#define KE 32
#define KI 20
#define LDW 65   // LDS tile leading stride in floats (64 cols + 1 pad).
                 // 65%32==1 -> row reads (lanes vary o, fixed col range) spread
                 // across all banks; col reads (lanes vary e) stay 2-way = free.

// output element offsets
#define OFF_H   0
#define OFF_POS 524288
#define OFF_F   536576
#define OFF_S   548864
#define OFF_C   794624
#define OFF_ST  1056768

typedef unsigned short u16;
typedef unsigned long long u64;

__device__ __forceinline__ float b2f(u16 u) {
  union { unsigned int i; float f; } c; c.i = ((unsigned int)u) << 16; return c.f;
}
__device__ __forceinline__ float silu_f(float x) { return x / (1.f + __expf(-x)); }
__device__ __forceinline__ void stout(void* out, int fp32m, size_t i, float v) {
  if (fp32m) ((float*)out)[i] = v;
  else ((__hip_bfloat16*)out)[i] = __float2bfloat16(v);
}

// ---------------- dtype probe: are float inputs fp32 or bf16? ----------------
__global__ void probe_dtype(const u16* __restrict__ h, int* __restrict__ flag) {
  if (threadIdx.x == 0) atomicExch(flag, 0);
  __syncthreads();
  int bad = 0;
  for (int i = threadIdx.x; i < 8192; i += 256) {
    float v = b2f(h[i]);
    if (!(v > -1000.f && v < 1000.f)) bad = 1;  // catches NaN too
  }
  if (bad) atomicOr(flag, 1);  // 1 => inputs are fp32
}

// ---------------- convert all float tensors -> fp32 workspace ----------------
struct CvtTable {
  const void* src[25];
  int dstoff[25];
  int cnt[25];
};

__global__ void convert_all(CvtTable tab, float* __restrict__ wsf, const int* __restrict__ flag) {
  const int seg = blockIdx.y;
  const int i = blockIdx.x * 256 + threadIdx.x;
  if (i >= tab.cnt[seg]) return;
  float v;
  if (*flag) v = ((const float*)tab.src[seg])[i];
  else       v = b2f(((const u16*)tab.src[seg])[i]);
  wsf[tab.dstoff[seg] + i] = v;
}

// ---------------- graph boundaries from sorted batch ----------------
__global__ void graph_bounds(const int* __restrict__ batch, int* __restrict__ gstart) {
  int n = blockIdx.x * 256 + threadIdx.x;
  if (n >= NN) return;
  int v = batch[n];
  int pv = (n == 0) ? -1 : batch[n - 1];
  for (int b = pv + 1; b <= v; b++) gstart[b] = n;
  if (n == NN - 1) for (int b = v + 1; b <= 32; b++) gstart[b] = NN;
}

// ---------------- exact k-NN within cutoff (one wave per node) ----------------
__global__ __launch_bounds__(256) void neigh_kernel(
    const float* __restrict__ pos, const int* __restrict__ batch,
    const int* __restrict__ gstart, int* __restrict__ idx, int* __restrict__ cnt,
    int Ksel, float cut2) {
  const int lane = threadIdx.x & 63;
  const int i = blockIdx.x * 4 + (threadIdx.x >> 6);
  const int b = batch[i];
  const int gs = gstart[b];
  const int ge = gstart[b + 1];
  const int span = ge - gs;  // wave-uniform
  const float px = pos[i * 3 + 0], py = pos[i * 3 + 1], pz = pos[i * 3 + 2];
  u64 key[16];
#pragma unroll
  for (int tq = 0; tq < 16; tq++) {
    u64 k64 = ~0ull;
    if (tq * 64 < span) {
      int j = gs + tq * 64 + lane;
      if (j < ge && j != i) {
        float dx = px - pos[j * 3 + 0];
        float dy = py - pos[j * 3 + 1];
        float dz = pz - pos[j * 3 + 2];
        float d2 = dx * dx + dy * dy + dz * dz;
        if (d2 <= cut2) k64 = (((u64)__float_as_uint(d2)) << 32) | (unsigned int)j;
      }
    }
    key[tq] = k64;
  }
  u64 thresh = 0;
  int myidx = i;
  int mycnt = 0;
  for (int s = 0; s < Ksel; s++) {
    u64 m = ~0ull;
#pragma unroll
    for (int tq = 0; tq < 16; tq++) {
      if (tq * 64 < span) {
        u64 kk = key[tq];
        if (kk >= thresh && kk < m) m = kk;
      }
    }
    for (int off = 32; off > 0; off >>= 1) {
      u64 o = __shfl_down(m, (unsigned)off, 64);
      if (o < m) m = o;
    }
    m = __shfl(m, 0, 64);
    if (m != ~0ull) {
      if (lane == s) myidx = (int)(m & 0xffffffffu);
      mycnt++;
      thresh = m + 1;
    } else break;
  }
  if (lane < Ksel) idx[i * Ksel + lane] = myidx;
  if (lane == 0) cnt[i] = mycnt;
}

// Scalar-weight stage core. Wave owns a uniform 16-output slice [o0, o0+16);
// lanes own the 64 edge-columns (2 nodes x 32 slots). Weight addresses are
// wave-uniform (o0 from readfirstlane) -> SMEM s_load (64 B/f/wave) instead of
// the old per-lane global dwordx4 (1 KB/f/wave, 8x redundant, ~60% of per-CU
// L2 share). X is one ds_read_b32/f at stride LDW (2-way bank = free; imm
// offset f*260 < 64K so the address is a single VGPR base). Per-accumulator
// chain is f-ascending fmaf -- bit-identical to the previous stage16.
__device__ __forceinline__ void stageS(const float* __restrict__ Wg, int o0,
                                       const float* __restrict__ Xe,
                                       float acc[16]) {
#pragma unroll 2
  for (int f = 0; f < HD; f++) {
    const float x = Xe[f * LDW];
    const float* w = Wg + (size_t)f * HD + o0;  // wave-uniform -> s_load
#pragma unroll
    for (int oj = 0; oj < 16; oj++) acc[oj] = fmaf(w[oj], x, acc[oj]);
  }
}

// ---------------- one EGNN layer, one block per 2 nodes ----------------
__global__ __launch_bounds__(512, 4) void egnn_layer(
    const float* __restrict__ h_in, const float* __restrict__ pos_in,
    float* __restrict__ h_out, float* __restrict__ pos_out,
    const int* __restrict__ idx, const int* __restrict__ cnt,
    const float* __restrict__ ew1, const float* __restrict__ eb1,
    const float* __restrict__ ew2, const float* __restrict__ eb2,
    const float* __restrict__ cw1, const float* __restrict__ cb1,
    const float* __restrict__ cw2,
    const float* __restrict__ nw1, const float* __restrict__ nb1,
    const float* __restrict__ nw2, const float* __restrict__ nb2) {
  __shared__ __align__(16) float bufA[HD * LDW];   // [f][64 cols]
  __shared__ __align__(16) float bufB[HD * LDW];
  __shared__ float hi_s[2][HD], hpart_s[2][HD], msum_s[2][HD], u_s[2][HD];
  __shared__ float red_s[512], red2_s[512];
  __shared__ float rel_s[3][64], d2_s[64], mf_s[64], ce_s[64];
  __shared__ int idx_s[64], cn_s[2];

  const int t = threadIdx.x;
  const int i0 = blockIdx.x * 2;
  const int e = t & 63;                                   // lane column
  const int wid = __builtin_amdgcn_readfirstlane(t >> 6); // 0..7, uniform
  const int o0 = wid * 16;                                // wave's output slice

  if (t < 64) idx_s[t] = idx[(size_t)(i0 + (t >> 5)) * KE + (t & 31)];
  else if (t < 66) cn_s[t - 64] = cnt[i0 + (t - 64)];
  if (t >= 256) {
    const int nt = t - 256;
    hi_s[nt >> 7][nt & 127] = h_in[(size_t)(i0 + (nt >> 7)) * HD + (nt & 127)];
  }
  __syncthreads();

  if (t < 64) {
    const int nd = t >> 5, ic = i0 + nd;
    const int j = idx_s[t];
    const float rx = pos_in[ic * 3 + 0] - pos_in[j * 3 + 0];
    const float ry = pos_in[ic * 3 + 1] - pos_in[j * 3 + 1];
    const float rz = pos_in[ic * 3 + 2] - pos_in[j * 3 + 2];
    rel_s[0][t] = rx; rel_s[1][t] = ry; rel_s[2][t] = rz;
    d2_s[t] = rx * rx + ry * ry + rz * rz;
    mf_s[t] = ((t & 31) < cn_s[nd]) ? 1.0f : 0.0f;
  }
  // gather hj -> bufA[f][e] (each wave stages a 16-f slab for all 64 cols)
  {
    const int f0 = (t >> 6) * 16;
    const int j = idx_s[e];
    const float4* src = (const float4*)(h_in + (size_t)j * HD + f0);
#pragma unroll
    for (int q = 0; q < 4; q++) {
      float4 v = src[q];
      const int fb = f0 + q * 4;
      bufA[(fb + 0) * LDW + e] = v.x;
      bufA[(fb + 1) * LDW + e] = v.y;
      bufA[(fb + 2) * LDW + e] = v.z;
      bufA[(fb + 3) * LDW + e] = v.w;
    }
  }
  // hpart[nd][o] = hi . ew1[0:128, o]  (edge-invariant half of edge MLP1)
  // same two-half f-split chain as before: (f0..63) + (f64..127) + eb1
  {
    const int oo = t & 127, nd = (t >> 7) & 1, hf = t >> 8;
    const float* hsrc = hi_s[nd];
    float hp = 0.f;
#pragma unroll 4
    for (int f = hf * 64; f < hf * 64 + 64; f++) hp = fmaf(hsrc[f], ew1[f * HD + oo], hp);
    red_s[t] = hp;
  }
  __syncthreads();
  if (t < 256) hpart_s[t >> 7][t & 127] = red_s[t] + red_s[t + 256] + eb1[t & 127];
  __syncthreads();

  // ---- stage B: m1 = silu(hpart + hj @ ew1[128:256] + d2*ew1[256]) -> bufB ----
  {
    const int nd = e >> 5;
    float acc[16];
#pragma unroll
    for (int oj = 0; oj < 16; oj++) acc[oj] = hpart_s[nd][o0 + oj];
    stageS(ew1 + 128 * HD, o0, bufA + e, acc);
    const float d2v = d2_s[e];
    const float* w2 = ew1 + 256 * HD + o0;  // uniform -> s_load
#pragma unroll
    for (int oj = 0; oj < 16; oj++)
      bufB[(o0 + oj) * LDW + e] = silu_f(fmaf(w2[oj], d2v, acc[oj]));
  }
  __syncthreads();

  // ---- stage C: m2 = mask ? silu(m1 @ ew2 + eb2) : 0 -> bufA ----
  {
    float acc[16];
#pragma unroll
    for (int oj = 0; oj < 16; oj++) acc[oj] = eb2[o0 + oj];
    stageS(ew2, o0, bufB + e, acc);
    const float mfv = mf_s[e];
#pragma unroll
    for (int oj = 0; oj < 16; oj++)
      bufA[(o0 + oj) * LDW + e] = (mfv != 0.f) ? silu_f(acc[oj]) : 0.f;
  }
  __syncthreads();

  // ---- stage D: c1 = silu(m2 @ cw1 + cb1); fold cw2 dot in-register ----
  // per-(e) chain: partial over this wave's 16 o's ascending, then 8 wave
  // partials summed ascending -> identical order to the old oc-group scheme.
  {
    float acc[16];
#pragma unroll
    for (int oj = 0; oj < 16; oj++) acc[oj] = cb1[o0 + oj];
    stageS(cw1, o0, bufA + e, acc);
    const float* c2 = cw2 + o0;  // uniform -> s_load
    float p = 0.f;
#pragma unroll
    for (int oj = 0; oj < 16; oj++) p = fmaf(silu_f(acc[oj]), c2[oj], p);
    red_s[t] = p;
  }
  // ---- msum partials: bufA (m2) is stable now; row-reads are conflict-free
  // thanks to LDW=65 (banks spread by oo). Same 16+16 half-split as before.
  {
    const int oo = t & 127, q = t >> 7;  // q = nd*2 + eh
    const int base = oo * LDW + (q >> 1) * 32 + (q & 1) * 16;
    float p = 0.f;
#pragma unroll
    for (int u = 0; u < 16; u++) p += bufA[base + u];
    red2_s[t] = p;
  }
  __syncthreads();
  if (t < 64) {
    float c = 0.f;
#pragma unroll
    for (int wv = 0; wv < 8; wv++) c += red_s[wv * 64 + t];
    ce_s[t] = (mf_s[t] != 0.f) ? c : 0.f;
  }
  if (t < 256) {
    const int nd = t >> 7, oo = t & 127;
    msum_s[nd][oo] = red2_s[nd * 256 + oo] + red2_s[nd * 256 + 128 + oo];
  }
  __syncthreads();
  // ---- pos update (per node, ascending-e chain as before) ----
  if (t < 6) {
    const int nd = t / 3, ax = t - nd * 3, ic = i0 + nd;
    float s = 0.f;
#pragma unroll
    for (int k = 0; k < 32; k++) s = fmaf(rel_s[ax][nd * 32 + k], ce_s[nd * 32 + k], s);
    const float cntf = fmaxf((float)cn_s[nd], 1.f);
    pos_out[ic * 3 + ax] = pos_in[ic * 3 + ax] + s / cntf;
  }
  // ---- node MLP1 (hi-part + msum-part halves, same chain) ----
  {
    const int oo = t & 127, nd = (t >> 7) & 1, ph = t >> 8;
    const float* src = ph ? msum_s[nd] : hi_s[nd];
    const float* Wp = nw1 + (size_t)ph * 128 * HD + oo;
    float p = 0.f;
#pragma unroll 4
    for (int f = 0; f < 128; f++) p = fmaf(src[f], Wp[f * HD], p);
    red_s[t] = p;
  }
  __syncthreads();
  if (t < 256) u_s[t >> 7][t & 127] = silu_f(red_s[t] + red_s[t + 256] + nb1[t & 127]);
  __syncthreads();
  // ---- node MLP2 + residual ----
  {
    const int oo = t & 127, nd = (t >> 7) & 1, ph = t >> 8;
    const float* up = u_s[nd] + ph * 64;
    const float* Wp = nw2 + (size_t)ph * 64 * HD + oo;
    float p = 0.f;
#pragma unroll 4
    for (int f = 0; f < 64; f++) p = fmaf(up[f], Wp[f * HD], p);
    red_s[t] = p;
  }
  __syncthreads();
  if (t < 256) {
    const int nd = t >> 7, oo = t & 127;
    h_out[(size_t)(i0 + nd) * HD + oo] = hi_s[nd][oo] + red_s[t] + red_s[t + 256] + nb2[oo];
  }
}

// ---------------- final heads (per node) ----------------
__global__ __launch_bounds__(256) void heads_kernel(
    const float* __restrict__ h, const float* __restrict__ pos,
    const float* __restrict__ fw1, const float* __restrict__ fb1,
    const float* __restrict__ fw2, const float* __restrict__ fb2,
    const float* __restrict__ cw1g, const float* __restrict__ cb1g,
    const float* __restrict__ cw2g, const float* __restrict__ cb2g,
    const float* __restrict__ sw, const float* __restrict__ sb,
    const float* __restrict__ iw,
    float* __restrict__ At, float* __restrict__ Bt,
    void* __restrict__ out, const int* __restrict__ flag) {
  __shared__ float hi_s[HD], v1[HD], red_s[256];
  const int i = blockIdx.x, t = threadIdx.x;
  const int fm = *flag;
  if (t < HD) hi_s[t] = h[(size_t)i * HD + t];
  __syncthreads();
  const int o = t & 127, ph = t >> 7;
  // forces MLP1
  {
    float p = 0.f;
#pragma unroll 4
    for (int f = ph * 64; f < ph * 64 + 64; f++) p = fmaf(hi_s[f], fw1[f * HD + o], p);
    red_s[t] = p;
  }
  __syncthreads();
  if (t < HD) v1[t] = tanhf(red_s[t] + red_s[t + 128] + fb1[t]);
  __syncthreads();
  if (t < 3) {
    float p = 0.f;
    for (int f = 0; f < HD; f++) p = fmaf(v1[f], fw2[f * 3 + t], p);
    stout(out, fm, OFF_F + (size_t)i * 3 + t, p + fb2[t]);
  }
  __syncthreads();
  // conformer MLP1
  {
    float p = 0.f;
#pragma unroll 4
    for (int f = ph * 64; f < ph * 64 + 64; f++) p = fmaf(hi_s[f], cw1g[f * HD + o], p);
    red_s[t] = p;
  }
  __syncthreads();
  if (t < HD) v1[t] = fmaxf(red_s[t] + red_s[t + 128] + cb1g[t], 0.f);
  __syncthreads();
  // conformer MLP2
  {
    const int oo = t & 63, pc = t >> 6;
    float p = 0.f;
#pragma unroll 4
    for (int f = pc * 32; f < pc * 32 + 32; f++) p = fmaf(v1[f], cw2g[f * 64 + oo], p);
    red_s[t] = p;
  }
  __syncthreads();
  if (t < 64)
    stout(out, fm, OFF_C + (size_t)i * 64 + t,
          red_s[t] + red_s[t + 64] + red_s[t + 128] + red_s[t + 192] + cb2g[t]);
  __syncthreads();
  // steric
  if (t < HD) red_s[t] = hi_s[t] * sw[t];
  __syncthreads();
  if (t == 0) {
    float p = 0.f;
    for (int f = 0; f < HD; f++) p += red_s[f];
    stout(out, fm, OFF_ST + (size_t)i, p + sb[0]);
  }
  __syncthreads();
  // interaction head per-node dots
  {
    const int g = t >> 5, l = t & 31;
    float p = 0.f;
    if (g < 6) {
      const int tt = g >> 1, half = g & 1;
#pragma unroll
      for (int r2 = 0; r2 < 4; r2++)
        p = fmaf(hi_s[l * 4 + r2], iw[tt * 258 + half * 128 + l * 4 + r2], p);
    }
    red_s[t] = p;
  }
  __syncthreads();
  if (t < 6) {
    float p = 0.f;
    for (int l = 0; l < 32; l++) p += red_s[t * 32 + l];
    const int tt = t >> 1;
    if ((t & 1) == 0) At[tt * NN + i] = p;
    else Bt[tt * NN + i] = p;
  }
  if (t < HD) stout(out, fm, OFF_H + (size_t)i * HD + t, hi_s[t]);
  if (t >= 128 && t < 131) stout(out, fm, OFF_POS + (size_t)i * 3 + (t - 128), pos[i * 3 + (t - 128)]);
}

// ---------------- interaction scores ----------------
__global__ void scores_kernel(const float* __restrict__ pos, const int* __restrict__ idx2,
                              const int* __restrict__ cnt2, const float* __restrict__ At,
                              const float* __restrict__ Bt, const float* __restrict__ iw,
                              const float* __restrict__ ib, void* __restrict__ out,
                              const int* __restrict__ flag) {
  int tid = blockIdx.x * 256 + threadIdx.x;
  if (tid >= 3 * NN * KI) return;
  const int fm = *flag;
  const int tt = tid / (NN * KI);
  const int r = tid % (NN * KI);
  const int n = r / KI;
  const int k = r % KI;
  float v = 0.f;
  if (k < cnt2[n]) {
    int j = idx2[n * KI + k];
    float dx = pos[n * 3 + 0] - pos[j * 3 + 0];
    float dy = pos[n * 3 + 1] - pos[j * 3 + 1];
    float dz = pos[n * 3 + 2] - pos[j * 3 + 2];
    float d2 = dx * dx + dy * dy + dz * dz;
    float dist = sqrtf(d2 + 1e-12f);
    float s = At[tt * NN + n] + Bt[tt * NN + j] + dist * iw[tt * 258 + 256] +
              (dist * 0.1f) * iw[tt * 258 + 257] + ib[tt];
    v = 1.f / (1.f + __expf(-s));
  }
  stout(out, fm, OFF_S + (size_t)tid, v);
}

extern "C" void kernel_launch(void* const* d_in, const int* in_sizes, int n_in,
                              void* d_out, int out_size, void* d_ws, size_t ws_size,
                              hipStream_t stream) {
  (void)in_sizes; (void)n_in; (void)out_size; (void)ws_size;

  float* wsf = (float*)d_ws;
  float* h_a = wsf + 0;             // 524288
  float* pos_a = wsf + 524288;      // 12288
  float* h_b = wsf + 536576;        // 524288
  float* pos_b = wsf + 1060864;     // 12288
  float* At = wsf + 1073152;        // 12288
  float* Bt = wsf + 1085440;        // 12288
  const int W0 = 1097728;

  static const int wcnt[23] = {197376, 768, 98304, 768, 98304, 768, 768,
                               196608, 768, 98304, 768, 16384, 128, 384, 3,
                               774, 3, 16384, 128, 8192, 64, 128, 1};
  int woff[23];
  {
    int o = W0;
    for (int k = 0; k < 23; k++) { woff[k] = o; o += wcnt[k]; }
  }
  const int IOFF = woff[22] + wcnt[22];
  int* ibase = (int*)d_ws;
  int* idx1 = ibase + IOFF;
  int* cnt1 = idx1 + NN * KE;
  int* idx2 = cnt1 + NN;
  int* cnt2 = idx2 + NN * KI;
  int* gstart = cnt2 + NN;
  int* flag = gstart + 33;

  const float* EW1 = wsf + woff[0];
  const float* EB1 = wsf + woff[1];
  const float* EW2 = wsf + woff[2];
  const float* EB2 = wsf + woff[3];
  const float* CW1 = wsf + woff[4];
  const float* CB1 = wsf + woff[5];
  const float* CW2 = wsf + woff[6];
  const float* NW1 = wsf + woff[7];
  const float* NB1 = wsf + woff[8];
  const float* NW2 = wsf + woff[9];
  const float* NB2 = wsf + woff[10];
  const float* FW1 = wsf + woff[11];
  const float* FB1 = wsf + woff[12];
  const float* FW2 = wsf + woff[13];
  const float* FB2 = wsf + woff[14];
  const float* IW = wsf + woff[15];
  const float* IB = wsf + woff[16];
  const float* CW1G = wsf + woff[17];
  const float* CB1G = wsf + woff[18];
  const float* CW2G = wsf + woff[19];
  const float* CB2G = wsf + woff[20];
  const float* SW = wsf + woff[21];
  const float* SB = wsf + woff[22];

  probe_dtype<<<1, 256, 0, stream>>>((const u16*)d_in[0], flag);

  CvtTable tab;
  tab.src[0] = d_in[0]; tab.dstoff[0] = 0;       tab.cnt[0] = NN * HD;
  tab.src[1] = d_in[1]; tab.dstoff[1] = 524288;  tab.cnt[1] = NN * 3;
  for (int k = 0; k < 23; k++) {
    tab.src[2 + k] = d_in[3 + k];
    tab.dstoff[2 + k] = woff[k];
    tab.cnt[2 + k] = wcnt[k];
  }
  {
    dim3 g((NN * HD + 255) / 256, 25, 1);
    convert_all<<<g, 256, 0, stream>>>(tab, wsf, flag);
  }

  const int* batch = (const int*)d_in[2];
  graph_bounds<<<NN / 256, 256, 0, stream>>>(batch, gstart);

  const float cut2s[3] = {9.f, 36.f, 100.f};
  float *hin = h_a, *pin = pos_a, *hout = h_b, *pout = pos_b;
  for (int l = 0; l < 6; l++) {
    if ((l & 1) == 0)
      neigh_kernel<<<NN / 4, 256, 0, stream>>>(pin, batch, gstart, idx1, cnt1, KE, cut2s[l >> 1]);
    egnn_layer<<<NN / 2, 512, 0, stream>>>(
        hin, pin, hout, pout, idx1, cnt1,
        EW1 + (size_t)l * 257 * HD, EB1 + (size_t)l * HD,
        EW2 + (size_t)l * HD * HD, EB2 + (size_t)l * HD,
        CW1 + (size_t)l * HD * HD, CB1 + (size_t)l * HD,
        CW2 + (size_t)l * HD,
        NW1 + (size_t)l * 256 * HD, NB1 + (size_t)l * HD,
        NW2 + (size_t)l * HD * HD, NB2 + (size_t)l * HD);
    float* th = hin; hin = hout; hout = th;
    float* tp = pin; pin = pout; pout = tp;
  }
  neigh_kernel<<<NN / 4, 256, 0, stream>>>(pin, batch, gstart, idx2, cnt2, KI, 100.f);
  heads_kernel<<<NN, 256, 0, stream>>>(hin, pin, FW1, FB1, FW2, FB2, CW1G, CB1G, CW2G, CB2G,
                                       SW, SB, IW, At, Bt, d_out, flag);
  scores_kernel<<<(3 * NN * KI + 255) / 256, 256, 0, stream>>>(
      pin, idx2, cnt2, At, Bt, IW, IB, d_out, flag);
}

// Round 2
// 951.996 us; speedup vs baseline: 1.8080x; 1.8080x over previous
//
#include <hip/hip_runtime.h>
#include <hip/hip_bf16.h>

#define NN 4096
#define HD 128
#define KE 32
#define KI 20
#define XLD 132  // packed-X LDS row stride in dwords: 132%32=4 -> every access
                 // pattern (A-frag b128 reads, epilogue b32 writes) is <=2-way

// output element offsets
#define OFF_H   0
#define OFF_POS 524288
#define OFF_F   536576
#define OFF_S   548864
#define OFF_C   794624
#define OFF_ST  1056768

typedef unsigned short u16;
typedef unsigned long long u64;
typedef __attribute__((ext_vector_type(8))) short bf16x8;   // 8 bf16 (4 VGPR)
typedef __attribute__((ext_vector_type(4))) float f32x4;

#define PERM_HI 0x07060302u  // D = [S1.hi16, S0.hi16]
#define PERM_LO 0x05040100u  // D = [S1.lo16, S0.lo16]

__device__ __forceinline__ float b2f(u16 u) {
  union { unsigned int i; float f; } c; c.i = ((unsigned int)u) << 16; return c.f;
}
__device__ __forceinline__ float silu_f(float x) { return x / (1.f + __expf(-x)); }
__device__ __forceinline__ void stout(void* out, int fp32m, size_t i, float v) {
  if (fp32m) ((float*)out)[i] = v;
  else ((__hip_bfloat16*)out)[i] = __float2bfloat16(v);
}
// RNE float->bf16 bits
__device__ __forceinline__ unsigned int f2b(float f) {
  unsigned int u = __float_as_uint(f);
  return (u + 0x7fffu + ((u >> 16) & 1u)) >> 16;
}
// pack (hi,lo) bf16 split of fp32 into one u32: hi in bytes 2-3, lo in bytes 0-1
__device__ __forceinline__ unsigned int packhl(float v) {
  unsigned int hb = f2b(v);
  float hf = __uint_as_float(hb << 16);
  unsigned int lb = f2b(v - hf);
  return (hb << 16) | lb;
}
__device__ __forceinline__ bf16x8 mk8(unsigned int a, unsigned int b,
                                      unsigned int c, unsigned int d) {
  union { unsigned int u[4]; bf16x8 v; } t;
  t.u[0] = a; t.u[1] = b; t.u[2] = c; t.u[3] = d; return t.v;
}

// ---------------- dtype probe: are float inputs fp32 or bf16? ----------------
__global__ void probe_dtype(const u16* __restrict__ h, int* __restrict__ flag) {
  if (threadIdx.x == 0) atomicExch(flag, 0);
  __syncthreads();
  int bad = 0;
  for (int i = threadIdx.x; i < 8192; i += 256) {
    float v = b2f(h[i]);
    if (!(v > -1000.f && v < 1000.f)) bad = 1;
  }
  if (bad) atomicOr(flag, 1);
}

// ---------------- convert all float tensors -> fp32 workspace ----------------
struct CvtTable {
  const void* src[25];
  int dstoff[25];
  int cnt[25];
};

__global__ void convert_all(CvtTable tab, float* __restrict__ wsf, const int* __restrict__ flag) {
  const int seg = blockIdx.y;
  const int i = blockIdx.x * 256 + threadIdx.x;
  if (i >= tab.cnt[seg]) return;
  float v;
  if (*flag) v = ((const float*)tab.src[seg])[i];
  else       v = b2f(((const u16*)tab.src[seg])[i]);
  wsf[tab.dstoff[seg] + i] = v;
}

// ---------------- pack stage weights into MFMA B-fragment order --------------
// B-frag layout for mfma_f32_16x16x32_bf16: lane l holds B[k][col] with
// col = l&15, k = (l>>4)*8 + j, j=0..7 contiguous -> one dwordx4 per frag.
// Output: [mat 18][kt 4][ot 8][lane 64][j 8] bf16, separate hi and lo arrays.
__global__ void pack_weights(const float* __restrict__ wsf, int offEW1, int offEW2, int offCW1,
                             u16* __restrict__ WBH, u16* __restrict__ WBL) {
  int tid = blockIdx.x * 256 + threadIdx.x;
  if (tid >= 18 * 16384) return;
  int m = tid >> 14;
  int rix = tid & 16383;
  int layer = m / 3, s = m % 3;
  const float* src;
  if (s == 0)      src = wsf + offEW1 + (size_t)layer * 257 * HD + 128 * HD;
  else if (s == 1) src = wsf + offEW2 + (size_t)layer * HD * HD;
  else             src = wsf + offCW1 + (size_t)layer * HD * HD;
  int j = rix & 7, lane = (rix >> 3) & 63, ot = (rix >> 9) & 7, kt = rix >> 12;
  int f = kt * 32 + (lane >> 4) * 8 + j;
  int o = ot * 16 + (lane & 15);
  float v = src[f * HD + o];
  unsigned int hb = f2b(v);
  float hf = __uint_as_float(hb << 16);
  unsigned int lb = f2b(v - hf);
  WBH[tid] = (u16)hb;
  WBL[tid] = (u16)lb;
}

// ---------------- graph boundaries from sorted batch ----------------
__global__ void graph_bounds(const int* __restrict__ batch, int* __restrict__ gstart) {
  int n = blockIdx.x * 256 + threadIdx.x;
  if (n >= NN) return;
  int v = batch[n];
  int pv = (n == 0) ? -1 : batch[n - 1];
  for (int b = pv + 1; b <= v; b++) gstart[b] = n;
  if (n == NN - 1) for (int b = v + 1; b <= 32; b++) gstart[b] = NN;
}

// ---------------- exact k-NN within cutoff (one wave per node) ----------------
__global__ __launch_bounds__(256) void neigh_kernel(
    const float* __restrict__ pos, const int* __restrict__ batch,
    const int* __restrict__ gstart, int* __restrict__ idx, int* __restrict__ cnt,
    int Ksel, float cut2) {
  const int lane = threadIdx.x & 63;
  const int i = blockIdx.x * 4 + (threadIdx.x >> 6);
  const int b = batch[i];
  const int gs = gstart[b];
  const int ge = gstart[b + 1];
  const int span = ge - gs;
  const float px = pos[i * 3 + 0], py = pos[i * 3 + 1], pz = pos[i * 3 + 2];
  u64 key[16];
#pragma unroll
  for (int tq = 0; tq < 16; tq++) {
    u64 k64 = ~0ull;
    if (tq * 64 < span) {
      int j = gs + tq * 64 + lane;
      if (j < ge && j != i) {
        float dx = px - pos[j * 3 + 0];
        float dy = py - pos[j * 3 + 1];
        float dz = pz - pos[j * 3 + 2];
        float d2 = dx * dx + dy * dy + dz * dz;
        if (d2 <= cut2) k64 = (((u64)__float_as_uint(d2)) << 32) | (unsigned int)j;
      }
    }
    key[tq] = k64;
  }
  u64 thresh = 0;
  int myidx = i;
  int mycnt = 0;
  for (int s = 0; s < Ksel; s++) {
    u64 m = ~0ull;
#pragma unroll
    for (int tq = 0; tq < 16; tq++) {
      if (tq * 64 < span) {
        u64 kk = key[tq];
        if (kk >= thresh && kk < m) m = kk;
      }
    }
    for (int off = 32; off > 0; off >>= 1) {
      u64 o = __shfl_down(m, (unsigned)off, 64);
      if (o < m) m = o;
    }
    m = __shfl(m, 0, 64);
    if (m != ~0ull) {
      if (lane == s) myidx = (int)(m & 0xffffffffu);
      mycnt++;
      thresh = m + 1;
    } else break;
  }
  if (lane < Ksel) idx[i * Ksel + lane] = myidx;
  if (lane == 0) cnt[i] = mycnt;
}

// 3-term split-bf16 MFMA stage: OUT[e][o] = sum_f X[e][f]*W[f][o] computed as
// Xhi*Whi + Xhi*Wlo + Xlo*Whi in fp32 accumulators (rel err ~2^-17).
// Wave owns e-tile E (16 e) x 4 o-tiles starting at ob. A-frag: lane l reads
// X row e=E*16+(l&15), k-run (l>>4)*8 (2x ds_read_b128 + 8 v_perm per kt).
// B-frags: one dwordx4 each from pre-packed global (L2-hot, shared by all blocks).
__device__ __forceinline__ void mfma_stage(const unsigned int* xin,
                                           const u16* __restrict__ WH,
                                           const u16* __restrict__ WL,
                                           int E, int ob, int lane, f32x4 acc[4]) {
  const int l16 = lane & 15, q = lane >> 4;
  const unsigned int* xr = xin + (E * 16 + l16) * XLD + q * 8;
  f32x4 z = {0.f, 0.f, 0.f, 0.f};
  acc[0] = z; acc[1] = z; acc[2] = z; acc[3] = z;
#pragma unroll
  for (int kt = 0; kt < 4; kt++) {
    uint4 xa = *(const uint4*)(xr + kt * 32);
    uint4 xb = *(const uint4*)(xr + kt * 32 + 4);
    bf16x8 ah = mk8(__builtin_amdgcn_perm(xa.y, xa.x, PERM_HI),
                    __builtin_amdgcn_perm(xa.w, xa.z, PERM_HI),
                    __builtin_amdgcn_perm(xb.y, xb.x, PERM_HI),
                    __builtin_amdgcn_perm(xb.w, xb.z, PERM_HI));
    bf16x8 al = mk8(__builtin_amdgcn_perm(xa.y, xa.x, PERM_LO),
                    __builtin_amdgcn_perm(xa.w, xa.z, PERM_LO),
                    __builtin_amdgcn_perm(xb.y, xb.x, PERM_LO),
                    __builtin_amdgcn_perm(xb.w, xb.z, PERM_LO));
#pragma unroll
    for (int ot = 0; ot < 4; ot++) {
      const int off = ((kt * 8 + ob + ot) * 64 + lane) * 8;
      bf16x8 wh = *(const bf16x8*)(WH + off);
      bf16x8 wl = *(const bf16x8*)(WL + off);
      acc[ot] = __builtin_amdgcn_mfma_f32_16x16x32_bf16(al, wh, acc[ot], 0, 0, 0);
      acc[ot] = __builtin_amdgcn_mfma_f32_16x16x32_bf16(ah, wl, acc[ot], 0, 0, 0);
      acc[ot] = __builtin_amdgcn_mfma_f32_16x16x32_bf16(ah, wh, acc[ot], 0, 0, 0);
    }
  }
}

// ---------------- one EGNN layer, one block per 2 nodes ----------------
__global__ __launch_bounds__(512, 4) void egnn_layer(
    const float* __restrict__ h_in, const float* __restrict__ pos_in,
    float* __restrict__ h_out, float* __restrict__ pos_out,
    const int* __restrict__ idx, const int* __restrict__ cnt,
    const float* __restrict__ ew1, const float* __restrict__ eb1,
    const float* __restrict__ eb2,
    const float* __restrict__ cb1, const float* __restrict__ cw2,
    const float* __restrict__ nw1, const float* __restrict__ nb1,
    const float* __restrict__ nw2, const float* __restrict__ nb2,
    const u16* __restrict__ wbh, const u16* __restrict__ wbl) {
  __shared__ __align__(16) unsigned int xpA[64 * XLD];  // packed hi|lo X, [e][f]
  __shared__ __align__(16) unsigned int xpB[64 * XLD];
  __shared__ float hi_s[2][HD], hpart_s[2][HD], msum_s[2][HD], u_s[2][HD];
  __shared__ float red_s[512];
  __shared__ float msum_red[4][HD];   // per-e-tile partial msum
  __shared__ float ce_red[64][2];     // per-e partial c-dot (o halves)
  __shared__ float rel_s[3][64], d2_s[64], mf_s[64], ce_s[64];
  __shared__ int idx_s[64], cn_s[2];

  const int t = threadIdx.x;
  const int i0 = blockIdx.x * 2;
  const int e = t & 63;
  const int lane = t & 63;
  const int wid8 = __builtin_amdgcn_readfirstlane(t >> 6);  // 0..7
  const int E = wid8 & 3;            // e-tile (16 edges)
  const int ob = (wid8 >> 2) * 4;    // first o-tile (4 tiles = 64 outputs)
  const int l16 = lane & 15, q = lane >> 4;

  if (t < 64) idx_s[t] = idx[(size_t)(i0 + (t >> 5)) * KE + (t & 31)];
  else if (t < 66) cn_s[t - 64] = cnt[i0 + (t - 64)];
  if (t >= 256) {
    const int nt = t - 256;
    hi_s[nt >> 7][nt & 127] = h_in[(size_t)(i0 + (nt >> 7)) * HD + (nt & 127)];
  }
  __syncthreads();

  if (t < 64) {
    const int nd = t >> 5, ic = i0 + nd;
    const int j = idx_s[t];
    const float rx = pos_in[ic * 3 + 0] - pos_in[j * 3 + 0];
    const float ry = pos_in[ic * 3 + 1] - pos_in[j * 3 + 1];
    const float rz = pos_in[ic * 3 + 2] - pos_in[j * 3 + 2];
    rel_s[0][t] = rx; rel_s[1][t] = ry; rel_s[2][t] = rz;
    d2_s[t] = rx * rx + ry * ry + rz * rz;
    mf_s[t] = ((t & 31) < cn_s[nd]) ? 1.0f : 0.0f;
  }
  // gather hj -> xpA[e][f] packed hi|lo (wave stages a 16-f slab for its cols)
  {
    const int j = idx_s[e];
    const int f0 = (t >> 6) * 16;
    const float4* src = (const float4*)(h_in + (size_t)j * HD + f0);
    unsigned int* dst = xpA + e * XLD + f0;
#pragma unroll
    for (int qq = 0; qq < 4; qq++) {
      float4 v = src[qq];
      dst[qq * 4 + 0] = packhl(v.x);
      dst[qq * 4 + 1] = packhl(v.y);
      dst[qq * 4 + 2] = packhl(v.z);
      dst[qq * 4 + 3] = packhl(v.w);
    }
  }
  // hpart[nd][o] = hi . ew1[0:128, o]  (edge-invariant half of edge MLP1)
  {
    const int oo = t & 127, nd = (t >> 7) & 1, hf = t >> 8;
    const float* hsrc = hi_s[nd];
    float hp = 0.f;
#pragma unroll
    for (int f4 = hf * 16; f4 < hf * 16 + 16; f4++) {
      float4 xv = *(const float4*)(hsrc + f4 * 4);
      hp = fmaf(xv.x, ew1[(f4 * 4 + 0) * HD + oo], hp);
      hp = fmaf(xv.y, ew1[(f4 * 4 + 1) * HD + oo], hp);
      hp = fmaf(xv.z, ew1[(f4 * 4 + 2) * HD + oo], hp);
      hp = fmaf(xv.w, ew1[(f4 * 4 + 3) * HD + oo], hp);
    }
    red_s[t] = hp;
  }
  __syncthreads();
  if (t < 256) hpart_s[t >> 7][t & 127] = red_s[t] + red_s[t + 256] + eb1[t & 127];
  __syncthreads();

  // ---- stage B: m1 = silu(hpart + hj @ ew1[128:256] + d2*ew1[256]) -> xpB ----
  {
    f32x4 acc[4];
    mfma_stage(xpA, wbh, wbl, E, ob, lane, acc);
    const int nd = E >> 1;
    float d2v[4];
#pragma unroll
    for (int r = 0; r < 4; r++) d2v[r] = d2_s[E * 16 + q * 4 + r];
#pragma unroll
    for (int ot = 0; ot < 4; ot++) {
      const int o = (ob + ot) * 16 + l16;
      const float hp = hpart_s[nd][o];
      const float w2 = ew1[256 * HD + o];
#pragma unroll
      for (int r = 0; r < 4; r++) {
        const int ee = E * 16 + q * 4 + r;
        float v = acc[ot][r] + hp + d2v[r] * w2;
        xpB[ee * XLD + o] = packhl(silu_f(v));
      }
    }
  }
  __syncthreads();

  // ---- stage C: m2 = mask ? silu(m1 @ ew2 + eb2) : 0 -> xpA; msum partials ----
  {
    f32x4 acc[4];
    mfma_stage(xpB, wbh + 16384, wbl + 16384, E, ob, lane, acc);
    float mfv[4];
#pragma unroll
    for (int r = 0; r < 4; r++) mfv[r] = mf_s[E * 16 + q * 4 + r];
    float msp[4] = {0.f, 0.f, 0.f, 0.f};
#pragma unroll
    for (int ot = 0; ot < 4; ot++) {
      const int o = (ob + ot) * 16 + l16;
      const float bb = eb2[o];
#pragma unroll
      for (int r = 0; r < 4; r++) {
        const int ee = E * 16 + q * 4 + r;
        float mm = (mfv[r] != 0.f) ? silu_f(acc[ot][r] + bb) : 0.f;
        msp[ot] += mm;
        xpA[ee * XLD + o] = packhl(mm);
      }
    }
    // reduce msum over the 4 q-groups (e within tile); write per-tile partial
#pragma unroll
    for (int ot = 0; ot < 4; ot++) {
      float s = msp[ot];
      s += __shfl_xor(s, 16);
      s += __shfl_xor(s, 32);
      msp[ot] = s;
    }
    if (lane < 16) {
#pragma unroll
      for (int ot = 0; ot < 4; ot++) msum_red[E][(ob + ot) * 16 + lane] = msp[ot];
    }
  }
  __syncthreads();

  // ---- stage D: c1 = silu(m2 @ cw1 + cb1); fold cw2 dot in-register ----
  {
    f32x4 acc[4];
    mfma_stage(xpA, wbh + 32768, wbl + 32768, E, ob, lane, acc);
    float cp[4] = {0.f, 0.f, 0.f, 0.f};
#pragma unroll
    for (int ot = 0; ot < 4; ot++) {
      const int o = (ob + ot) * 16 + l16;
      const float b1 = cb1[o];
      const float c2 = cw2[o];
#pragma unroll
      for (int r = 0; r < 4; r++)
        cp[r] = fmaf(silu_f(acc[ot][r] + b1), c2, cp[r]);
    }
#pragma unroll
    for (int r = 0; r < 4; r++) {
      float s = cp[r];
      s += __shfl_xor(s, 1);
      s += __shfl_xor(s, 2);
      s += __shfl_xor(s, 4);
      s += __shfl_xor(s, 8);
      cp[r] = s;
    }
    if (l16 == 0) {
#pragma unroll
      for (int r = 0; r < 4; r++) ce_red[E * 16 + q * 4 + r][ob >> 2] = cp[r];
    }
  }
  __syncthreads();
  if (t < 64) ce_s[t] = (mf_s[t] != 0.f) ? (ce_red[t][0] + ce_red[t][1]) : 0.f;
  if (t < 256) {
    const int nd = t >> 7, oo = t & 127;
    msum_s[nd][oo] = msum_red[nd * 2][oo] + msum_red[nd * 2 + 1][oo];
  }
  __syncthreads();
  // ---- pos update ----
  if (t < 6) {
    const int nd = t / 3, ax = t - nd * 3, ic = i0 + nd;
    float s = 0.f;
#pragma unroll
    for (int k = 0; k < 32; k++) s = fmaf(rel_s[ax][nd * 32 + k], ce_s[nd * 32 + k], s);
    const float cntf = fmaxf((float)cn_s[nd], 1.f);
    pos_out[ic * 3 + ax] = pos_in[ic * 3 + ax] + s / cntf;
  }
  // ---- node MLP1 ----
  {
    const int oo = t & 127, nd = (t >> 7) & 1, ph = t >> 8;
    const float* src = ph ? msum_s[nd] : hi_s[nd];
    const float* Wp = nw1 + (size_t)ph * 128 * HD + oo;
    float p = 0.f;
#pragma unroll
    for (int f4 = 0; f4 < 32; f4++) {
      float4 xv = *(const float4*)(src + f4 * 4);
      p = fmaf(xv.x, Wp[(f4 * 4 + 0) * HD], p);
      p = fmaf(xv.y, Wp[(f4 * 4 + 1) * HD], p);
      p = fmaf(xv.z, Wp[(f4 * 4 + 2) * HD], p);
      p = fmaf(xv.w, Wp[(f4 * 4 + 3) * HD], p);
    }
    red_s[t] = p;
  }
  __syncthreads();
  if (t < 256) u_s[t >> 7][t & 127] = silu_f(red_s[t] + red_s[t + 256] + nb1[t & 127]);
  __syncthreads();
  // ---- node MLP2 + residual ----
  {
    const int oo = t & 127, nd = (t >> 7) & 1, ph = t >> 8;
    const float* src = u_s[nd] + ph * 64;
    const float* Wp = nw2 + (size_t)ph * 64 * HD + oo;
    float p = 0.f;
#pragma unroll
    for (int f4 = 0; f4 < 16; f4++) {
      float4 xv = *(const float4*)(src + f4 * 4);
      p = fmaf(xv.x, Wp[(f4 * 4 + 0) * HD], p);
      p = fmaf(xv.y, Wp[(f4 * 4 + 1) * HD], p);
      p = fmaf(xv.z, Wp[(f4 * 4 + 2) * HD], p);
      p = fmaf(xv.w, Wp[(f4 * 4 + 3) * HD], p);
    }
    red_s[t] = p;
  }
  __syncthreads();
  if (t < 256) {
    const int nd = t >> 7, oo = t & 127;
    h_out[(size_t)(i0 + nd) * HD + oo] = hi_s[nd][oo] + red_s[t] + red_s[t + 256] + nb2[oo];
  }
}

// ---------------- final heads (per node) ----------------
__global__ __launch_bounds__(256) void heads_kernel(
    const float* __restrict__ h, const float* __restrict__ pos,
    const float* __restrict__ fw1, const float* __restrict__ fb1,
    const float* __restrict__ fw2, const float* __restrict__ fb2,
    const float* __restrict__ cw1g, const float* __restrict__ cb1g,
    const float* __restrict__ cw2g, const float* __restrict__ cb2g,
    const float* __restrict__ sw, const float* __restrict__ sb,
    const float* __restrict__ iw,
    float* __restrict__ At, float* __restrict__ Bt,
    void* __restrict__ out, const int* __restrict__ flag) {
  __shared__ float hi_s[HD], v1[HD], red_s[256];
  const int i = blockIdx.x, t = threadIdx.x;
  const int fm = *flag;
  if (t < HD) hi_s[t] = h[(size_t)i * HD + t];
  __syncthreads();
  const int o = t & 127, ph = t >> 7;
  // forces MLP1
  {
    float p = 0.f;
#pragma unroll 4
    for (int f = ph * 64; f < ph * 64 + 64; f++) p = fmaf(hi_s[f], fw1[f * HD + o], p);
    red_s[t] = p;
  }
  __syncthreads();
  if (t < HD) v1[t] = tanhf(red_s[t] + red_s[t + 128] + fb1[t]);
  __syncthreads();
  if (t < 3) {
    float p = 0.f;
    for (int f = 0; f < HD; f++) p = fmaf(v1[f], fw2[f * 3 + t], p);
    stout(out, fm, OFF_F + (size_t)i * 3 + t, p + fb2[t]);
  }
  __syncthreads();
  // conformer MLP1
  {
    float p = 0.f;
#pragma unroll 4
    for (int f = ph * 64; f < ph * 64 + 64; f++) p = fmaf(hi_s[f], cw1g[f * HD + o], p);
    red_s[t] = p;
  }
  __syncthreads();
  if (t < HD) v1[t] = fmaxf(red_s[t] + red_s[t + 128] + cb1g[t], 0.f);
  __syncthreads();
  // conformer MLP2
  {
    const int oo = t & 63, pc = t >> 6;
    float p = 0.f;
#pragma unroll 4
    for (int f = pc * 32; f < pc * 32 + 32; f++) p = fmaf(v1[f], cw2g[f * 64 + oo], p);
    red_s[t] = p;
  }
  __syncthreads();
  if (t < 64)
    stout(out, fm, OFF_C + (size_t)i * 64 + t,
          red_s[t] + red_s[t + 64] + red_s[t + 128] + red_s[t + 192] + cb2g[t]);
  __syncthreads();
  // steric
  if (t < HD) red_s[t] = hi_s[t] * sw[t];
  __syncthreads();
  if (t == 0) {
    float p = 0.f;
    for (int f = 0; f < HD; f++) p += red_s[f];
    stout(out, fm, OFF_ST + (size_t)i, p + sb[0]);
  }
  __syncthreads();
  // interaction head per-node dots
  {
    const int g = t >> 5, l = t & 31;
    float p = 0.f;
    if (g < 6) {
      const int tt = g >> 1, half = g & 1;
#pragma unroll
      for (int r2 = 0; r2 < 4; r2++)
        p = fmaf(hi_s[l * 4 + r2], iw[tt * 258 + half * 128 + l * 4 + r2], p);
    }
    red_s[t] = p;
  }
  __syncthreads();
  if (t < 6) {
    float p = 0.f;
    for (int l = 0; l < 32; l++) p += red_s[t * 32 + l];
    const int tt = t >> 1;
    if ((t & 1) == 0) At[tt * NN + i] = p;
    else Bt[tt * NN + i] = p;
  }
  if (t < HD) stout(out, fm, OFF_H + (size_t)i * HD + t, hi_s[t]);
  if (t >= 128 && t < 131) stout(out, fm, OFF_POS + (size_t)i * 3 + (t - 128), pos[i * 3 + (t - 128)]);
}

// ---------------- interaction scores ----------------
__global__ void scores_kernel(const float* __restrict__ pos, const int* __restrict__ idx2,
                              const int* __restrict__ cnt2, const float* __restrict__ At,
                              const float* __restrict__ Bt, const float* __restrict__ iw,
                              const float* __restrict__ ib, void* __restrict__ out,
                              const int* __restrict__ flag) {
  int tid = blockIdx.x * 256 + threadIdx.x;
  if (tid >= 3 * NN * KI) return;
  const int fm = *flag;
  const int tt = tid / (NN * KI);
  const int r = tid % (NN * KI);
  const int n = r / KI;
  const int k = r % KI;
  float v = 0.f;
  if (k < cnt2[n]) {
    int j = idx2[n * KI + k];
    float dx = pos[n * 3 + 0] - pos[j * 3 + 0];
    float dy = pos[n * 3 + 1] - pos[j * 3 + 1];
    float dz = pos[n * 3 + 2] - pos[j * 3 + 2];
    float d2 = dx * dx + dy * dy + dz * dz;
    float dist = sqrtf(d2 + 1e-12f);
    float s = At[tt * NN + n] + Bt[tt * NN + j] + dist * iw[tt * 258 + 256] +
              (dist * 0.1f) * iw[tt * 258 + 257] + ib[tt];
    v = 1.f / (1.f + __expf(-s));
  }
  stout(out, fm, OFF_S + (size_t)tid, v);
}

extern "C" void kernel_launch(void* const* d_in, const int* in_sizes, int n_in,
                              void* d_out, int out_size, void* d_ws, size_t ws_size,
                              hipStream_t stream) {
  (void)in_sizes; (void)n_in; (void)out_size; (void)ws_size;

  float* wsf = (float*)d_ws;
  float* h_a = wsf + 0;             // 524288
  float* pos_a = wsf + 524288;      // 12288
  float* h_b = wsf + 536576;        // 524288
  float* pos_b = wsf + 1060864;     // 12288
  float* At = wsf + 1073152;        // 12288
  float* Bt = wsf + 1085440;        // 12288
  const int W0 = 1097728;

  static const int wcnt[23] = {197376, 768, 98304, 768, 98304, 768, 768,
                               196608, 768, 98304, 768, 16384, 128, 384, 3,
                               774, 3, 16384, 128, 8192, 64, 128, 1};
  int woff[23];
  {
    int o = W0;
    for (int k = 0; k < 23; k++) { woff[k] = o; o += wcnt[k]; }
  }
  const int IOFF = woff[22] + wcnt[22];
  int* ibase = (int*)d_ws;
  int* idx1 = ibase + IOFF;
  int* cnt1 = idx1 + NN * KE;
  int* idx2 = cnt1 + NN;
  int* cnt2 = idx2 + NN * KI;
  int* gstart = cnt2 + NN;
  int* flag = gstart + 33;
  // packed MFMA weight fragments (bf16 hi/lo), 16B-aligned
  int wboff = (int)((flag + 1) - ibase);
  wboff = (wboff + 3) & ~3;
  u16* WBH = (u16*)(ibase + wboff);
  u16* WBL = WBH + 18 * 16384;

  const float* EW1 = wsf + woff[0];
  const float* EB1 = wsf + woff[1];
  const float* EB2 = wsf + woff[3];
  const float* CB1 = wsf + woff[5];
  const float* CW2 = wsf + woff[6];
  const float* NW1 = wsf + woff[7];
  const float* NB1 = wsf + woff[8];
  const float* NW2 = wsf + woff[9];
  const float* NB2 = wsf + woff[10];
  const float* FW1 = wsf + woff[11];
  const float* FB1 = wsf + woff[12];
  const float* FW2 = wsf + woff[13];
  const float* FB2 = wsf + woff[14];
  const float* IW = wsf + woff[15];
  const float* IB = wsf + woff[16];
  const float* CW1G = wsf + woff[17];
  const float* CB1G = wsf + woff[18];
  const float* CW2G = wsf + woff[19];
  const float* CB2G = wsf + woff[20];
  const float* SW = wsf + woff[21];
  const float* SB = wsf + woff[22];

  probe_dtype<<<1, 256, 0, stream>>>((const u16*)d_in[0], flag);

  CvtTable tab;
  tab.src[0] = d_in[0]; tab.dstoff[0] = 0;       tab.cnt[0] = NN * HD;
  tab.src[1] = d_in[1]; tab.dstoff[1] = 524288;  tab.cnt[1] = NN * 3;
  for (int k = 0; k < 23; k++) {
    tab.src[2 + k] = d_in[3 + k];
    tab.dstoff[2 + k] = woff[k];
    tab.cnt[2 + k] = wcnt[k];
  }
  {
    dim3 g((NN * HD + 255) / 256, 25, 1);
    convert_all<<<g, 256, 0, stream>>>(tab, wsf, flag);
  }
  pack_weights<<<(18 * 16384 + 255) / 256, 256, 0, stream>>>(
      wsf, woff[0], woff[2], woff[4], WBH, WBL);

  const int* batch = (const int*)d_in[2];
  graph_bounds<<<NN / 256, 256, 0, stream>>>(batch, gstart);

  const float cut2s[3] = {9.f, 36.f, 100.f};
  float *hin = h_a, *pin = pos_a, *hout = h_b, *pout = pos_b;
  for (int l = 0; l < 6; l++) {
    if ((l & 1) == 0)
      neigh_kernel<<<NN / 4, 256, 0, stream>>>(pin, batch, gstart, idx1, cnt1, KE, cut2s[l >> 1]);
    egnn_layer<<<NN / 2, 512, 0, stream>>>(
        hin, pin, hout, pout, idx1, cnt1,
        EW1 + (size_t)l * 257 * HD, EB1 + (size_t)l * HD,
        EB2 + (size_t)l * HD,
        CB1 + (size_t)l * HD, CW2 + (size_t)l * HD,
        NW1 + (size_t)l * 256 * HD, NB1 + (size_t)l * HD,
        NW2 + (size_t)l * HD * HD, NB2 + (size_t)l * HD,
        WBH + (size_t)l * 3 * 16384, WBL + (size_t)l * 3 * 16384);
    float* th = hin; hin = hout; hout = th;
    float* tp = pin; pin = pout; pout = tp;
  }
  neigh_kernel<<<NN / 4, 256, 0, stream>>>(pin, batch, gstart, idx2, cnt2, KI, 100.f);
  heads_kernel<<<NN, 256, 0, stream>>>(hin, pin, FW1, FB1, FW2, FB2, CW1G, CB1G, CW2G, CB2G,
                                       SW, SB, IW, At, Bt, d_out, flag);
  scores_kernel<<<(3 * NN * KI + 255) / 256, 256, 0, stream>>>(
      pin, idx2, cnt2, At, Bt, IW, IB, d_out, flag);
}